// Round 1
// baseline (188.684 us; speedup 1.0000x reference)
//
#include <hip/hip_runtime.h>
#include <hip/hip_bf16.h>

// MultiRelationalGraphDiffusion: out = LeakyReLU( sum_k conv_w[k] * (adj_norm^k @ (h@W^T)) + conv_b )
// B=8, N=2048, D=256, K=4 diffusion taps.
//
// Strategy:
//  - h@W^T in fp32 (accuracy-critical dominant term; no fp32 MFMA on CDNA4 but only 2.1 GFLOP)
//  - diffusion bmms in bf16 MFMA (51.5 GFLOP; row-stochastic averaging contracts bf16 noise ~40x)
//  - curr stored TRANSPOSED ([b][o][n], bf16) so MFMA B-fragments are K-contiguous (ds_read_b128)
//  - adj normalized+converted f32->bf16 in-register during staging; XOR chunk swizzle on LDS

#define BATCH 8
#define NN    2048
#define DD    256
#define REPS  1e-9f
#define SLOPE 0.2f

typedef __bf16 bf16x8_t __attribute__((ext_vector_type(8)));
typedef __bf16 bf16x4_t __attribute__((ext_vector_type(4)));
typedef float  f32x4_t  __attribute__((ext_vector_type(4)));

// ---------------- W transpose: Wt[i][o] = W[o][i] ----------------
__global__ __launch_bounds__(256) void k_transposeW(const float* __restrict__ W,
                                                    float* __restrict__ Wt) {
    int g = blockIdx.x * 256 + threadIdx.x;   // 65536 elems
    int o = g >> 8, i = g & 255;
    Wt[i * 256 + o] = W[g];
}

// ---------------- row sums of adj -> inv = 1/(sum+eps) ----------------
__global__ __launch_bounds__(256) void k_rowsum(const float* __restrict__ adj,
                                                float* __restrict__ inv) {
    int row = blockIdx.x;                       // b*NN + n, 0..16383
    const f32x4_t* p = (const f32x4_t*)(adj + (size_t)row * NN);
    int t = threadIdx.x;
    f32x4_t a = p[t], b = p[t + 256];
    float s = a[0] + a[1] + a[2] + a[3] + b[0] + b[1] + b[2] + b[3];
#pragma unroll
    for (int off = 32; off > 0; off >>= 1) s += __shfl_down(s, off, 64);
    __shared__ float sm[4];
    if ((t & 63) == 0) sm[t >> 6] = s;
    __syncthreads();
    if (t == 0) {
        float tot = sm[0] + sm[1] + sm[2] + sm[3];
        inv[row] = 1.0f / (tot + REPS);
    }
}

// ---------------- h_trans = h @ W^T (fp32), write out=cw0*t and curr0_T bf16 ----------------
// block: 64 rows (n) x 64 cols (o), 256 threads, each 4x4. K=256 in 4 tiles of 64.
__global__ __launch_bounds__(256) void k_htrans(const float* __restrict__ h,
                                                const float* __restrict__ Wt,
                                                const float* __restrict__ convw,
                                                float* __restrict__ out,
                                                __bf16* __restrict__ c0) {
    __shared__ float hs[64 * 68];   // hs[n][i]
    __shared__ float wst[64 * 68];  // wst[i][o]
    int tid = threadIdx.x;
    int n0 = blockIdx.x * 64, o0 = blockIdx.y * 64, b = blockIdx.z;
    int tx = tid & 15, ty = tid >> 4;
    int sn = tid >> 2, seg = tid & 3;   // staging: row 0..63, 16-float segment 0..3

    float acc[4][4] = {};

    for (int kt = 0; kt < 4; ++kt) {
        int k0 = kt * 64;
        __syncthreads();
#pragma unroll
        for (int q = 0; q < 4; ++q) {
            f32x4_t hv = *(const f32x4_t*)(h + ((size_t)b * NN + n0 + sn) * DD + k0 + seg * 16 + q * 4);
            *(f32x4_t*)&hs[sn * 68 + seg * 16 + q * 4] = hv;
            f32x4_t wv = *(const f32x4_t*)(Wt + (size_t)(k0 + sn) * DD + o0 + seg * 16 + q * 4);
            *(f32x4_t*)&wst[sn * 68 + seg * 16 + q * 4] = wv;
        }
        __syncthreads();
#pragma unroll
        for (int kk = 0; kk < 64; ++kk) {
            f32x4_t b4 = *(const f32x4_t*)&wst[kk * 68 + tx * 4];
            float a0 = hs[(ty * 4 + 0) * 68 + kk];
            float a1 = hs[(ty * 4 + 1) * 68 + kk];
            float a2 = hs[(ty * 4 + 2) * 68 + kk];
            float a3 = hs[(ty * 4 + 3) * 68 + kk];
#pragma unroll
            for (int c = 0; c < 4; ++c) {
                acc[0][c] += a0 * b4[c];
                acc[1][c] += a1 * b4[c];
                acc[2][c] += a2 * b4[c];
                acc[3][c] += a3 * b4[c];
            }
        }
    }

    float cw0 = convw[0];
    size_t obase = ((size_t)b * NN + n0 + ty * 4) * DD + o0 + tx * 4;
#pragma unroll
    for (int r = 0; r < 4; ++r) {
        f32x4_t v = {cw0 * acc[r][0], cw0 * acc[r][1], cw0 * acc[r][2], cw0 * acc[r][3]};
        *(f32x4_t*)(out + obase + (size_t)r * DD) = v;
    }
#pragma unroll
    for (int c = 0; c < 4; ++c) {
        bf16x4_t t4;
        t4[0] = (__bf16)acc[0][c];
        t4[1] = (__bf16)acc[1][c];
        t4[2] = (__bf16)acc[2][c];
        t4[3] = (__bf16)acc[3][c];
        *(bf16x4_t*)(c0 + ((size_t)b * DD + o0 + tx * 4 + c) * NN + n0 + ty * 4) = t4;
    }
}

// ---------------- diffusion step: curr' = adj_norm @ curr (bf16 MFMA) ----------------
// out += cw * curr'; non-last also writes curr'_T bf16. Last fuses +cb and LeakyReLU.
// block tile 64(M) x 128(N), BK=64, 4 waves (2x2), wave tile 32x64 = 2x4 fragments 16x16x32.
template <bool LAST>
__global__ __launch_bounds__(256) void k_diffuse(const float* __restrict__ adj,
                                                 const float* __restrict__ inv,
                                                 const __bf16* __restrict__ cin,
                                                 __bf16* __restrict__ cout,
                                                 float* __restrict__ out,
                                                 const float* __restrict__ convw,
                                                 const float* __restrict__ convb,
                                                 int kidx) {
    __shared__ __align__(16) __bf16 As[64 * 64];    // [row m-out 64][k 64], 16B-chunk swizzled
    __shared__ __align__(16) __bf16 Bs[128 * 64];   // [col o 128][k 64], 16B-chunk swizzled

    int tid  = threadIdx.x;
    int iBlk = blockIdx.x * 64;
    int oBase = blockIdx.y * 128;
    int b    = blockIdx.z;
    int lane = tid & 63, wv = tid >> 6;
    int wr = wv >> 1, wc = wv & 1;
    int rl = lane & 15, kq = lane >> 4;

    const float*  adjb = adj + (size_t)b * NN * NN;
    const __bf16* cinb = cin + (size_t)b * DD * NN;
    const float*  invp = inv + b * NN;

    int ar0 = tid >> 3;        // A staging row base (0..31), +32 for q=1
    int ach = tid & 7;         // 16B chunk within 128B row
    float iv0 = invp[iBlk + ar0];
    float iv1 = invp[iBlk + ar0 + 32];

    f32x4_t acc[2][4];
#pragma unroll
    for (int i = 0; i < 2; ++i)
#pragma unroll
        for (int j = 0; j < 4; ++j) acc[i][j] = (f32x4_t){0.f, 0.f, 0.f, 0.f};

    for (int t = 0; t < NN / 64; ++t) {
        int k0 = t * 64;
        // ---- stage A: normalize f32 adj row-tile -> bf16, swizzled ds_write_b128
#pragma unroll
        for (int q = 0; q < 2; ++q) {
            int r = ar0 + q * 32;
            float iv = q ? iv1 : iv0;
            const float* src = adjb + (size_t)(iBlk + r) * NN + k0 + ach * 8;
            f32x4_t f0 = *(const f32x4_t*)src;
            f32x4_t f1 = *(const f32x4_t*)(src + 4);
            bf16x8_t v;
            v[0] = (__bf16)(f0[0] * iv); v[1] = (__bf16)(f0[1] * iv);
            v[2] = (__bf16)(f0[2] * iv); v[3] = (__bf16)(f0[3] * iv);
            v[4] = (__bf16)(f1[0] * iv); v[5] = (__bf16)(f1[1] * iv);
            v[6] = (__bf16)(f1[2] * iv); v[7] = (__bf16)(f1[3] * iv);
            *(bf16x8_t*)(As + (((r << 3) | (ach ^ (r & 7))) << 3)) = v;
        }
        // ---- stage B: copy bf16 curr_T tile (already K-contiguous), swizzled
#pragma unroll
        for (int q = 0; q < 4; ++q) {
            int c = tid + q * 256;
            int r = c >> 3, ch = c & 7;
            uint4 v = *(const uint4*)(cinb + (size_t)(oBase + r) * NN + k0 + ch * 8);
            *(uint4*)(Bs + (((r << 3) | (ch ^ (r & 7))) << 3)) = v;
        }
        __syncthreads();
        // ---- MFMA: 2 k-subs of 32, frags a[2], b[4], 16 MFMAs/iter
#pragma unroll
        for (int s = 0; s < 2; ++s) {
            bf16x8_t a[2], bb[4];
#pragma unroll
            for (int i = 0; i < 2; ++i) {
                int row = wr * 32 + i * 16 + rl;
                a[i] = *(const bf16x8_t*)(As + (((row << 3) | ((s * 4 + kq) ^ (row & 7))) << 3));
            }
#pragma unroll
            for (int j = 0; j < 4; ++j) {
                int o = wc * 64 + j * 16 + rl;
                bb[j] = *(const bf16x8_t*)(Bs + (((o << 3) | ((s * 4 + kq) ^ (o & 7))) << 3));
            }
#pragma unroll
            for (int i = 0; i < 2; ++i)
#pragma unroll
                for (int j = 0; j < 4; ++j)
                    acc[i][j] = __builtin_amdgcn_mfma_f32_16x16x32_bf16(a[i], bb[j], acc[i][j], 0, 0, 0);
        }
        __syncthreads();
    }

    // ---- epilogue: D frag layout col=lane&15, row=(lane>>4)*4+reg (m89-verified)
    float cw = convw[kidx];
    float cb = LAST ? convb[0] : 0.0f;
#pragma unroll
    for (int i = 0; i < 2; ++i) {
#pragma unroll
        for (int j = 0; j < 4; ++j) {
            int row0 = iBlk + wr * 32 + i * 16 + kq * 4;
            int col  = oBase + wc * 64 + j * 16 + rl;
            float* op = out + ((size_t)b * NN + row0) * DD + col;
            if (LAST) {
#pragma unroll
                for (int r2 = 0; r2 < 4; ++r2) {
                    float v = op[r2 * DD] + cw * acc[i][j][r2] + cb;
                    op[r2 * DD] = v >= 0.0f ? v : SLOPE * v;
                }
            } else {
#pragma unroll
                for (int r2 = 0; r2 < 4; ++r2) op[r2 * DD] += cw * acc[i][j][r2];
                bf16x4_t t4;
                t4[0] = (__bf16)acc[i][j][0];
                t4[1] = (__bf16)acc[i][j][1];
                t4[2] = (__bf16)acc[i][j][2];
                t4[3] = (__bf16)acc[i][j][3];
                *(bf16x4_t*)(cout + ((size_t)b * DD + col) * NN + row0) = t4;
            }
        }
    }
}

extern "C" void kernel_launch(void* const* d_in, const int* in_sizes, int n_in,
                              void* d_out, int out_size, void* d_ws, size_t ws_size,
                              hipStream_t stream) {
    const float* h    = (const float*)d_in[0];
    const float* adj  = (const float*)d_in[1];
    const float* W    = (const float*)d_in[2];
    const float* cw   = (const float*)d_in[3];
    const float* cb   = (const float*)d_in[4];
    float* out = (float*)d_out;

    char* ws = (char*)d_ws;
    float*  Wt  = (float*)ws;                                   // 256 KB
    float*  inv = (float*)(ws + 262144);                        // 64 KB
    __bf16* c0  = (__bf16*)(ws + 262144 + 65536);               // 8 MB
    __bf16* c1  = (__bf16*)(ws + 262144 + 65536 + 8388608);     // 8 MB  (total ~17.1 MB)

    k_transposeW<<<256, 256, 0, stream>>>(W, Wt);
    k_rowsum<<<BATCH * NN, 256, 0, stream>>>(adj, inv);
    k_htrans<<<dim3(NN / 64, DD / 64, BATCH), 256, 0, stream>>>(h, Wt, cw, out, c0);
    k_diffuse<false><<<dim3(NN / 64, DD / 128, BATCH), 256, 0, stream>>>(adj, inv, c0, c1, out, cw, cb, 1);
    k_diffuse<false><<<dim3(NN / 64, DD / 128, BATCH), 256, 0, stream>>>(adj, inv, c1, c0, out, cw, cb, 2);
    k_diffuse<true ><<<dim3(NN / 64, DD / 128, BATCH), 256, 0, stream>>>(adj, inv, c0, c1, out, cw, cb, 3);
}

// Round 2
// 142.579 us; speedup vs baseline: 1.3234x; 1.3234x over previous
//
#include <hip/hip_runtime.h>
#include <hip/hip_bf16.h>
#include <cstdint>

// MultiRelationalGraphDiffusion: out = LeakyReLU( sum_k conv_w[k] * (adj_norm^k @ (h@W^T)) + conv_b )
// B=8, N=2048, D=256, K=4.
//
// Round-2 structure:
//  - k_prepW:   W -> W_hi/W_lo bf16 (bf16x3 split), PRE-SWIZZLED for global_load_lds staging
//  - k_normadj: fused rowsum + normalize + f32->bf16 + PRE-SWIZZLE (single pass, values in regs)
//  - k_htrans:  bf16x3 MFMA (hi*hi + hi*lo + lo*hi) -> out (f32) + curr0_T (bf16, pre-swizzled)
//  - k_diffuse: 64x128 tile, BK=64, global_load_lds(16) both operands from pre-swizzled
//               global layouts -> linear LDS, XOR applied on ds_read_b128 (2-way = free)
// Swizzle: within each 64-elem (128B) K-segment, 16B chunk index ch ^= (row & 7).

#define BATCH 8
#define NN    2048
#define DD    256
#define REPS  1e-9f
#define SLOPE 0.2f

typedef __bf16 bf16x8_t __attribute__((ext_vector_type(8)));
typedef __bf16 bf16x4_t __attribute__((ext_vector_type(4)));
typedef float  f32x4_t  __attribute__((ext_vector_type(4)));

__device__ __forceinline__ void gl2lds16(const void* g, void* l) {
    __builtin_amdgcn_global_load_lds(
        (const __attribute__((address_space(1))) unsigned int*)(uintptr_t)g,
        (__attribute__((address_space(3))) unsigned int*)(unsigned int)(uintptr_t)l,
        16, 0, 0);
}

// ---------------- W -> W_hi/W_lo bf16, pre-swizzled keyed by (o&7) ----------------
__global__ __launch_bounds__(256) void k_prepW(const float* __restrict__ W,
                                               __bf16* __restrict__ Whi,
                                               __bf16* __restrict__ Wlo) {
    const int g  = blockIdx.x * 256 + threadIdx.x;   // 8192 threads x 8 elems
    const int o  = g >> 5;
    const int i0 = (g & 31) * 8;
    const float* src = W + (size_t)o * DD + i0;
    f32x4_t v0 = *(const f32x4_t*)src;
    f32x4_t v1 = *(const f32x4_t*)(src + 4);
    bf16x8_t hi, lo;
#pragma unroll
    for (int e = 0; e < 4; ++e) {
        float a = v0[e]; __bf16 ha = (__bf16)a; hi[e]     = ha; lo[e]     = (__bf16)(a - (float)ha);
        float c = v1[e]; __bf16 hc = (__bf16)c; hi[e + 4] = hc; lo[e + 4] = (__bf16)(c - (float)hc);
    }
    const int cc = (i0 & ~63) | ((((i0 >> 3) & 7) ^ (o & 7)) << 3);
    *(bf16x8_t*)(Whi + (size_t)o * DD + cc) = hi;
    *(bf16x8_t*)(Wlo + (size_t)o * DD + cc) = lo;
}

// ---------------- fused rowsum + normalize + bf16 + pre-swizzle ----------------
__global__ __launch_bounds__(256) void k_normadj(const float* __restrict__ adj,
                                                 __bf16* __restrict__ adjn) {
    const int row = blockIdx.x;                 // b*NN + n ; row&7 == n&7
    const int t   = threadIdx.x;
    const float* src = adj + (size_t)row * NN;
    f32x4_t v0 = *(const f32x4_t*)(src + t * 8);
    f32x4_t v1 = *(const f32x4_t*)(src + t * 8 + 4);
    float s = v0[0] + v0[1] + v0[2] + v0[3] + v1[0] + v1[1] + v1[2] + v1[3];
#pragma unroll
    for (int off = 32; off > 0; off >>= 1) s += __shfl_down(s, off, 64);
    __shared__ float sm[4];
    if ((t & 63) == 0) sm[t >> 6] = s;
    __syncthreads();
    const float inv = 1.0f / (sm[0] + sm[1] + sm[2] + sm[3] + REPS);
    bf16x8_t o;
#pragma unroll
    for (int e = 0; e < 4; ++e) {
        o[e]     = (__bf16)(v0[e] * inv);
        o[e + 4] = (__bf16)(v1[e] * inv);
    }
    const int cc = (t >> 3) * 64 + (((t & 7) ^ (row & 7)) << 3);
    *(bf16x8_t*)(adjn + (size_t)row * NN + cc) = o;
}

// ---------------- h @ W^T via bf16x3 MFMA -> out f32, curr0_T bf16 swizzled ----------------
// tile 64(n) x 128(o), BK=64, 4 waves each 32x64 (2x4 frags of 16x16x32)
__global__ __launch_bounds__(256) void k_htrans(const float* __restrict__ h,
                                                const __bf16* __restrict__ Whi,
                                                const __bf16* __restrict__ Wlo,
                                                const float* __restrict__ convw,
                                                float* __restrict__ out,
                                                __bf16* __restrict__ c0) {
    __shared__ __align__(16) __bf16 Ah[64 * 64], Al[64 * 64];
    __shared__ __align__(16) __bf16 Bh[128 * 64], Bl[128 * 64];

    const int tid = threadIdx.x;
    const int n0 = blockIdx.x * 64, o0 = blockIdx.y * 128, b = blockIdx.z;
    const int lane = tid & 63, wv = tid >> 6;
    const int wr = wv >> 1, wc = wv & 1;
    const int rl = lane & 15, kq = lane >> 4;
    const int srow = lane >> 3, scol = (lane & 7) * 8;   // gload_lds source coords
    const int ar = tid >> 4, ac = (tid & 15) * 4;        // A reg-stage coords (f32)

    f32x4_t acc[2][4];
#pragma unroll
    for (int i = 0; i < 2; ++i)
#pragma unroll
        for (int j = 0; j < 4; ++j) acc[i][j] = (f32x4_t){0.f, 0.f, 0.f, 0.f};

    for (int kt = 0; kt < 4; ++kt) {
        const int k0 = kt * 64;
        // ---- A: load f32 h, split hi/lo, swizzled ds_write
#pragma unroll
        for (int q = 0; q < 4; ++q) {
            const int r = q * 16 + ar;
            f32x4_t v = *(const f32x4_t*)(h + ((size_t)b * NN + n0 + r) * DD + k0 + ac);
            bf16x4_t hi4, lo4;
#pragma unroll
            for (int e = 0; e < 4; ++e) {
                float x = v[e];
                __bf16 hh = (__bf16)x;
                hi4[e] = hh;
                lo4[e] = (__bf16)(x - (float)hh);
            }
            const int off = r * 128 + (((ac >> 3) ^ (r & 7)) << 4) + (ac & 7) * 2;
            *(bf16x4_t*)((char*)Ah + off) = hi4;
            *(bf16x4_t*)((char*)Al + off) = lo4;
        }
        // ---- B: global_load_lds from pre-swizzled Whi/Wlo (linear LDS)
#pragma unroll
        for (int q = 0; q < 4; ++q) {
            const int r = q * 32 + wv * 8 + srow;
            gl2lds16(Whi + (size_t)(o0 + r) * DD + k0 + scol, (char*)Bh + q * 4096 + wv * 1024);
            gl2lds16(Wlo + (size_t)(o0 + r) * DD + k0 + scol, (char*)Bl + q * 4096 + wv * 1024);
        }
        __syncthreads();
#pragma unroll
        for (int s = 0; s < 2; ++s) {
            bf16x8_t ah[2], al[2], bh[4], bl[4];
#pragma unroll
            for (int i = 0; i < 2; ++i) {
                const int row = wr * 32 + i * 16 + rl;
                const int byo = row * 128 + (((s * 4 + kq) ^ (row & 7)) << 4);
                ah[i] = *(const bf16x8_t*)((const char*)Ah + byo);
                al[i] = *(const bf16x8_t*)((const char*)Al + byo);
            }
#pragma unroll
            for (int j = 0; j < 4; ++j) {
                const int o = wc * 64 + j * 16 + rl;
                const int byo = o * 128 + (((s * 4 + kq) ^ (o & 7)) << 4);
                bh[j] = *(const bf16x8_t*)((const char*)Bh + byo);
                bl[j] = *(const bf16x8_t*)((const char*)Bl + byo);
            }
#pragma unroll
            for (int i = 0; i < 2; ++i)
#pragma unroll
                for (int j = 0; j < 4; ++j) {
                    acc[i][j] = __builtin_amdgcn_mfma_f32_16x16x32_bf16(ah[i], bh[j], acc[i][j], 0, 0, 0);
                    acc[i][j] = __builtin_amdgcn_mfma_f32_16x16x32_bf16(al[i], bh[j], acc[i][j], 0, 0, 0);
                    acc[i][j] = __builtin_amdgcn_mfma_f32_16x16x32_bf16(ah[i], bl[j], acc[i][j], 0, 0, 0);
                }
        }
        __syncthreads();
    }

    const float cw0 = convw[0];
#pragma unroll
    for (int i = 0; i < 2; ++i)
#pragma unroll
        for (int j = 0; j < 4; ++j) {
            const int row0 = n0 + wr * 32 + i * 16 + kq * 4;
            const int col  = o0 + wc * 64 + j * 16 + rl;
            float* op = out + ((size_t)b * NN + row0) * DD + col;
            bf16x4_t t4;
#pragma unroll
            for (int r2 = 0; r2 < 4; ++r2) {
                op[r2 * DD] = cw0 * acc[i][j][r2];
                t4[r2] = (__bf16)acc[i][j][r2];
            }
            const int nn2 = (row0 & ~63) | ((((row0 >> 3) & 7) ^ (col & 7)) << 3) | (row0 & 7);
            *(bf16x4_t*)(c0 + ((size_t)b * DD + col) * NN + nn2) = t4;
        }
}

// ---------------- diffusion step: curr' = adj_norm @ curr, all-gload_lds ----------------
template <bool LAST>
__global__ __launch_bounds__(256) void k_diffuse(const __bf16* __restrict__ adjn,
                                                 const __bf16* __restrict__ cin,
                                                 __bf16* __restrict__ cout,
                                                 float* __restrict__ out,
                                                 const float* __restrict__ convw,
                                                 const float* __restrict__ convb,
                                                 int kidx) {
    __shared__ __align__(16) __bf16 As[64 * 64];    // 8 KB
    __shared__ __align__(16) __bf16 Bs[128 * 64];   // 16 KB

    const int tid = threadIdx.x;
    const int n0 = blockIdx.x * 64, o0 = blockIdx.y * 128, b = blockIdx.z;
    const int lane = tid & 63, wv = tid >> 6;
    const int wr = wv >> 1, wc = wv & 1;
    const int rl = lane & 15, kq = lane >> 4;
    const int srow = lane >> 3, scol = (lane & 7) * 8;

    const __bf16* adjb = adjn + (size_t)b * NN * NN;
    const __bf16* cinb = cin + (size_t)b * DD * NN;

    f32x4_t acc[2][4];
#pragma unroll
    for (int i = 0; i < 2; ++i)
#pragma unroll
        for (int j = 0; j < 4; ++j) acc[i][j] = (f32x4_t){0.f, 0.f, 0.f, 0.f};

    for (int t = 0; t < NN / 64; ++t) {
        const int k0 = t * 64;
        // A: 8 KB (pre-swizzled source -> linear LDS)
#pragma unroll
        for (int q = 0; q < 2; ++q) {
            const int r = q * 32 + wv * 8 + srow;
            gl2lds16(adjb + (size_t)(n0 + r) * NN + k0 + scol, (char*)As + q * 4096 + wv * 1024);
        }
        // B: 16 KB
#pragma unroll
        for (int q = 0; q < 4; ++q) {
            const int r = q * 32 + wv * 8 + srow;
            gl2lds16(cinb + (size_t)(o0 + r) * NN + k0 + scol, (char*)Bs + q * 4096 + wv * 1024);
        }
        __syncthreads();
#pragma unroll
        for (int s = 0; s < 2; ++s) {
            bf16x8_t a[2], bb[4];
#pragma unroll
            for (int i = 0; i < 2; ++i) {
                const int row = wr * 32 + i * 16 + rl;
                a[i] = *(const bf16x8_t*)((const char*)As + row * 128 + (((s * 4 + kq) ^ (row & 7)) << 4));
            }
#pragma unroll
            for (int j = 0; j < 4; ++j) {
                const int o = wc * 64 + j * 16 + rl;
                bb[j] = *(const bf16x8_t*)((const char*)Bs + o * 128 + (((s * 4 + kq) ^ (o & 7)) << 4));
            }
#pragma unroll
            for (int i = 0; i < 2; ++i)
#pragma unroll
                for (int j = 0; j < 4; ++j)
                    acc[i][j] = __builtin_amdgcn_mfma_f32_16x16x32_bf16(a[i], bb[j], acc[i][j], 0, 0, 0);
        }
        __syncthreads();
    }

    const float cw = convw[kidx];
    const float cb = LAST ? convb[0] : 0.0f;
#pragma unroll
    for (int i = 0; i < 2; ++i)
#pragma unroll
        for (int j = 0; j < 4; ++j) {
            const int row0 = n0 + wr * 32 + i * 16 + kq * 4;
            const int col  = o0 + wc * 64 + j * 16 + rl;
            float* op = out + ((size_t)b * NN + row0) * DD + col;
            if (LAST) {
#pragma unroll
                for (int r2 = 0; r2 < 4; ++r2) {
                    float v = op[r2 * DD] + cw * acc[i][j][r2] + cb;
                    op[r2 * DD] = v >= 0.0f ? v : SLOPE * v;
                }
            } else {
#pragma unroll
                for (int r2 = 0; r2 < 4; ++r2) op[r2 * DD] += cw * acc[i][j][r2];
                bf16x4_t t4;
                t4[0] = (__bf16)acc[i][j][0];
                t4[1] = (__bf16)acc[i][j][1];
                t4[2] = (__bf16)acc[i][j][2];
                t4[3] = (__bf16)acc[i][j][3];
                const int nn2 = (row0 & ~63) | ((((row0 >> 3) & 7) ^ (col & 7)) << 3) | (row0 & 7);
                *(bf16x4_t*)(cout + ((size_t)b * DD + col) * NN + nn2) = t4;
            }
        }
}

extern "C" void kernel_launch(void* const* d_in, const int* in_sizes, int n_in,
                              void* d_out, int out_size, void* d_ws, size_t ws_size,
                              hipStream_t stream) {
    const float* h   = (const float*)d_in[0];
    const float* adj = (const float*)d_in[1];
    const float* W   = (const float*)d_in[2];
    const float* cw  = (const float*)d_in[3];
    const float* cb  = (const float*)d_in[4];
    float* out = (float*)d_out;

    char* ws = (char*)d_ws;
    __bf16* Whi  = (__bf16*)ws;                                   // 128 KB
    __bf16* Wlo  = (__bf16*)(ws + 131072);                        // 128 KB
    __bf16* adjn = (__bf16*)(ws + 262144);                        // 64 MB
    __bf16* c0   = (__bf16*)(ws + 262144 + 67108864);             // 8 MB
    __bf16* c1   = (__bf16*)(ws + 262144 + 67108864 + 8388608);   // 8 MB (~84 MB total)

    k_prepW<<<32, 256, 0, stream>>>(W, Whi, Wlo);
    k_normadj<<<BATCH * NN, 256, 0, stream>>>(adj, adjn);
    k_htrans<<<dim3(NN / 64, DD / 128, BATCH), 256, 0, stream>>>(h, Whi, Wlo, cw, out, c0);
    k_diffuse<false><<<dim3(NN / 64, DD / 128, BATCH), 256, 0, stream>>>(adjn, c0, c1, out, cw, cb, 1);
    k_diffuse<false><<<dim3(NN / 64, DD / 128, BATCH), 256, 0, stream>>>(adjn, c1, c0, out, cw, cb, 2);
    k_diffuse<true ><<<dim3(NN / 64, DD / 128, BATCH), 256, 0, stream>>>(adjn, c0, c1, out, cw, cb, 3);
}

// Round 3
// 130.934 us; speedup vs baseline: 1.4411x; 1.0889x over previous
//
#include <hip/hip_runtime.h>
#include <hip/hip_bf16.h>
#include <cstdint>

// MultiRelationalGraphDiffusion: out = LeakyReLU( sum_k conv_w[k] * (adj_norm^k @ (h@W^T)) + conv_b )
// B=8, N=2048, D=256, K=4.
//
// Round-3 structure:
//  - k_pre (fused): blocks [0,512) = h@W^T via bf16x3 MFMA (W hi/lo split in-kernel);
//                   blocks [512,16896) = fused rowsum+normalize+bf16+pre-swizzle of adj.
//                   BW-bound normadj hides the compute-bound htrans blocks.
//  - k_diffuse: 64x128 tile, BK=64, DOUBLE-BUFFERED LDS with stage-ahead-1
//               (issue next tile's global_load_lds before current tile's MFMA; one
//               __syncthreads per K-step whose vmcnt(0) drain is covered by compute).
//  - steps 1,2 write only curr_T (no out RMW); LAST step combines
//               out = lrelu(cw0*t + cw1*c1 + cw2*c2 + cw3*acc + cb).
// Swizzle: within each 64-elem (128B) K-segment, 16B chunk ch ^= (row & 7);
// sources pre-swizzled so global_load_lds stays linear (rule 21 / m173).

#define BATCH 8
#define NN    2048
#define DD    256
#define REPS  1e-9f
#define SLOPE 0.2f

typedef __bf16 bf16x8_t __attribute__((ext_vector_type(8)));
typedef __bf16 bf16x4_t __attribute__((ext_vector_type(4)));
typedef float  f32x4_t  __attribute__((ext_vector_type(4)));

__device__ __forceinline__ void gl2lds16(const void* g, void* l) {
    __builtin_amdgcn_global_load_lds(
        (const __attribute__((address_space(1))) unsigned int*)(uintptr_t)g,
        (__attribute__((address_space(3))) unsigned int*)(unsigned int)(uintptr_t)l,
        16, 0, 0);
}

// ================= fused pre-pass =================
// blocks [0,512): htrans tile 64(n) x 128(o); blocks [512,16896): normadj row = bid-512
__global__ __launch_bounds__(256) void k_pre(const float* __restrict__ h,
                                             const float* __restrict__ W,
                                             const float* __restrict__ adj,
                                             const float* __restrict__ convw,
                                             float* __restrict__ out,
                                             __bf16* __restrict__ c0,
                                             __bf16* __restrict__ adjn) {
    __shared__ __align__(16) char smem[49152];
    const int bid = blockIdx.x;
    const int tid = threadIdx.x;

    if (bid >= 512) {
        // ---------- normadj: fused rowsum + normalize + bf16 + pre-swizzle ----------
        const int row = bid - 512;                    // b*NN + n ; row&7 == n&7
        const float* src = adj + (size_t)row * NN;
        f32x4_t v0 = *(const f32x4_t*)(src + tid * 8);
        f32x4_t v1 = *(const f32x4_t*)(src + tid * 8 + 4);
        float s = v0[0] + v0[1] + v0[2] + v0[3] + v1[0] + v1[1] + v1[2] + v1[3];
#pragma unroll
        for (int off = 32; off > 0; off >>= 1) s += __shfl_down(s, off, 64);
        float* sm4 = (float*)smem;
        if ((tid & 63) == 0) sm4[tid >> 6] = s;
        __syncthreads();
        const float inv = 1.0f / (sm4[0] + sm4[1] + sm4[2] + sm4[3] + REPS);
        bf16x8_t o;
#pragma unroll
        for (int e = 0; e < 4; ++e) {
            o[e]     = (__bf16)(v0[e] * inv);
            o[e + 4] = (__bf16)(v1[e] * inv);
        }
        const int cc = (tid >> 3) * 64 + (((tid & 7) ^ (row & 7)) << 3);
        *(bf16x8_t*)(adjn + (size_t)row * NN + cc) = o;
        return;
    }

    // ---------- htrans: bf16x3 MFMA (hi*hi + lo*hi + hi*lo) ----------
    __bf16* Ah = (__bf16*)smem;            // 8 KB
    __bf16* Al = (__bf16*)(smem + 8192);   // 8 KB
    __bf16* Bh = (__bf16*)(smem + 16384);  // 16 KB
    __bf16* Bl = (__bf16*)(smem + 32768);  // 16 KB

    const int n0 = (bid & 31) * 64, o0 = ((bid >> 5) & 1) * 128, b = bid >> 6;
    const int lane = tid & 63, wv = tid >> 6;
    const int wr = wv >> 1, wc = wv & 1;
    const int rl = lane & 15, kq = lane >> 4;
    const int ar = tid >> 4, ac = (tid & 15) * 4;   // reg-stage coords (f32x4)

    f32x4_t acc[2][4];
#pragma unroll
    for (int i = 0; i < 2; ++i)
#pragma unroll
        for (int j = 0; j < 4; ++j) acc[i][j] = (f32x4_t){0.f, 0.f, 0.f, 0.f};

    for (int kt = 0; kt < 4; ++kt) {
        const int k0 = kt * 64;
        // A: h rows (64 x 64), split hi/lo, swizzled ds_write
#pragma unroll
        for (int q = 0; q < 4; ++q) {
            const int r = q * 16 + ar;
            f32x4_t v = *(const f32x4_t*)(h + ((size_t)b * NN + n0 + r) * DD + k0 + ac);
            bf16x4_t hi4, lo4;
#pragma unroll
            for (int e = 0; e < 4; ++e) {
                float x = v[e];
                __bf16 hh = (__bf16)x;
                hi4[e] = hh;
                lo4[e] = (__bf16)(x - (float)hh);
            }
            const int off = r * 128 + (((ac >> 3) ^ (r & 7)) << 4) + (ac & 7) * 2;
            *(bf16x4_t*)((char*)Ah + off) = hi4;
            *(bf16x4_t*)((char*)Al + off) = lo4;
        }
        // B: W rows (128 x 64), split hi/lo, swizzled ds_write
#pragma unroll
        for (int q = 0; q < 8; ++q) {
            const int r = q * 16 + ar;
            f32x4_t v = *(const f32x4_t*)(W + (size_t)(o0 + r) * DD + k0 + ac);
            bf16x4_t hi4, lo4;
#pragma unroll
            for (int e = 0; e < 4; ++e) {
                float x = v[e];
                __bf16 hh = (__bf16)x;
                hi4[e] = hh;
                lo4[e] = (__bf16)(x - (float)hh);
            }
            const int off = r * 128 + (((ac >> 3) ^ (r & 7)) << 4) + (ac & 7) * 2;
            *(bf16x4_t*)((char*)Bh + off) = hi4;
            *(bf16x4_t*)((char*)Bl + off) = lo4;
        }
        __syncthreads();
#pragma unroll
        for (int s = 0; s < 2; ++s) {
            bf16x8_t ah[2], al[2], bh[4], bl[4];
#pragma unroll
            for (int i = 0; i < 2; ++i) {
                const int row = wr * 32 + i * 16 + rl;
                const int byo = row * 128 + (((s * 4 + kq) ^ (row & 7)) << 4);
                ah[i] = *(const bf16x8_t*)((const char*)Ah + byo);
                al[i] = *(const bf16x8_t*)((const char*)Al + byo);
            }
#pragma unroll
            for (int j = 0; j < 4; ++j) {
                const int o = wc * 64 + j * 16 + rl;
                const int byo = o * 128 + (((s * 4 + kq) ^ (o & 7)) << 4);
                bh[j] = *(const bf16x8_t*)((const char*)Bh + byo);
                bl[j] = *(const bf16x8_t*)((const char*)Bl + byo);
            }
#pragma unroll
            for (int i = 0; i < 2; ++i)
#pragma unroll
                for (int j = 0; j < 4; ++j) {
                    acc[i][j] = __builtin_amdgcn_mfma_f32_16x16x32_bf16(ah[i], bh[j], acc[i][j], 0, 0, 0);
                    acc[i][j] = __builtin_amdgcn_mfma_f32_16x16x32_bf16(al[i], bh[j], acc[i][j], 0, 0, 0);
                    acc[i][j] = __builtin_amdgcn_mfma_f32_16x16x32_bf16(ah[i], bl[j], acc[i][j], 0, 0, 0);
                }
        }
        __syncthreads();
    }

    const float cw0 = convw[0];
#pragma unroll
    for (int i = 0; i < 2; ++i)
#pragma unroll
        for (int j = 0; j < 4; ++j) {
            const int row0 = n0 + wr * 32 + i * 16 + kq * 4;
            const int col  = o0 + wc * 64 + j * 16 + rl;
            float* op = out + ((size_t)b * NN + row0) * DD + col;
            bf16x4_t t4;
#pragma unroll
            for (int r2 = 0; r2 < 4; ++r2) {
                op[r2 * DD] = cw0 * acc[i][j][r2];
                t4[r2] = (__bf16)acc[i][j][r2];
            }
            const int nn2 = (row0 & ~63) | ((((row0 >> 3) & 7) ^ (col & 7)) << 3) | (row0 & 7);
            *(bf16x4_t*)(c0 + ((size_t)b * DD + col) * NN + nn2) = t4;
        }
}

// ================= diffusion step (double-buffered, stage-ahead-1) =================
__device__ __forceinline__ void stage_tile(const __bf16* __restrict__ adjRow,
                                           const __bf16* __restrict__ cinRow,
                                           char* As, char* Bs,
                                           int wv, int srow, int scol, int k0) {
#pragma unroll
    for (int q = 0; q < 2; ++q)
        gl2lds16(adjRow + (size_t)(q * 32 + wv * 8 + srow) * NN + k0 + scol,
                 As + q * 4096 + wv * 1024);
#pragma unroll
    for (int q = 0; q < 4; ++q)
        gl2lds16(cinRow + (size_t)(q * 32 + wv * 8 + srow) * NN + k0 + scol,
                 Bs + q * 4096 + wv * 1024);
}

template <bool LAST>
__global__ __launch_bounds__(256) void k_diffuse(const __bf16* __restrict__ adjn,
                                                 const __bf16* __restrict__ cin,
                                                 __bf16* __restrict__ cout,
                                                 const __bf16* __restrict__ c1T,
                                                 const __bf16* __restrict__ c2T,
                                                 float* __restrict__ out,
                                                 const float* __restrict__ convw,
                                                 const float* __restrict__ convb) {
    __shared__ __align__(16) __bf16 As[2][64 * 64];    // 2 x 8 KB
    __shared__ __align__(16) __bf16 Bs[2][128 * 64];   // 2 x 16 KB

    const int tid = threadIdx.x;
    const int n0 = blockIdx.x * 64, o0 = blockIdx.y * 128, b = blockIdx.z;
    const int lane = tid & 63, wv = tid >> 6;
    const int wr = wv >> 1, wc = wv & 1;
    const int rl = lane & 15, kq = lane >> 4;
    const int srow = lane >> 3, scol = (lane & 7) * 8;

    const __bf16* adjRow = adjn + (size_t)b * NN * NN + (size_t)n0 * NN;
    const __bf16* cinRow = cin + (size_t)b * DD * NN + (size_t)o0 * NN;

    f32x4_t acc[2][4];
#pragma unroll
    for (int i = 0; i < 2; ++i)
#pragma unroll
        for (int j = 0; j < 4; ++j) acc[i][j] = (f32x4_t){0.f, 0.f, 0.f, 0.f};

    stage_tile(adjRow, cinRow, (char*)As[0], (char*)Bs[0], wv, srow, scol, 0);
    __syncthreads();

#pragma unroll 2
    for (int t = 0; t < NN / 64; ++t) {
        const int pb = t & 1;
        if (t < NN / 64 - 1)
            stage_tile(adjRow, cinRow, (char*)As[pb ^ 1], (char*)Bs[pb ^ 1],
                       wv, srow, scol, (t + 1) * 64);
        const char* Ac = (const char*)As[pb];
        const char* Bc = (const char*)Bs[pb];
#pragma unroll
        for (int s = 0; s < 2; ++s) {
            bf16x8_t a[2], bb[4];
#pragma unroll
            for (int i = 0; i < 2; ++i) {
                const int row = wr * 32 + i * 16 + rl;
                a[i] = *(const bf16x8_t*)(Ac + row * 128 + (((s * 4 + kq) ^ (row & 7)) << 4));
            }
#pragma unroll
            for (int j = 0; j < 4; ++j) {
                const int o = wc * 64 + j * 16 + rl;
                bb[j] = *(const bf16x8_t*)(Bc + o * 128 + (((s * 4 + kq) ^ (o & 7)) << 4));
            }
#pragma unroll
            for (int i = 0; i < 2; ++i)
#pragma unroll
                for (int j = 0; j < 4; ++j)
                    acc[i][j] = __builtin_amdgcn_mfma_f32_16x16x32_bf16(a[i], bb[j], acc[i][j], 0, 0, 0);
        }
        __syncthreads();   // drains vmcnt(0) (stage-ahead loads) + lgkm; protects buffer reuse
    }

    // ---- epilogue ----
#pragma unroll
    for (int i = 0; i < 2; ++i)
#pragma unroll
        for (int j = 0; j < 4; ++j) {
            const int row0 = n0 + wr * 32 + i * 16 + kq * 4;
            const int col  = o0 + wc * 64 + j * 16 + rl;
            const int nn2 = (row0 & ~63) | ((((row0 >> 3) & 7) ^ (col & 7)) << 3) | (row0 & 7);
            if (LAST) {
                const float cw1 = convw[1], cw2 = convw[2], cw3 = convw[3];
                const float cb  = convb[0];
                float* op = out + ((size_t)b * NN + row0) * DD + col;
                bf16x4_t u1 = *(const bf16x4_t*)(c1T + ((size_t)b * DD + col) * NN + nn2);
                bf16x4_t u2 = *(const bf16x4_t*)(c2T + ((size_t)b * DD + col) * NN + nn2);
#pragma unroll
                for (int r2 = 0; r2 < 4; ++r2) {
                    float v = op[r2 * DD] + cw1 * (float)u1[r2] + cw2 * (float)u2[r2]
                            + cw3 * acc[i][j][r2] + cb;
                    op[r2 * DD] = v >= 0.0f ? v : SLOPE * v;
                }
            } else {
                bf16x4_t t4;
                t4[0] = (__bf16)acc[i][j][0];
                t4[1] = (__bf16)acc[i][j][1];
                t4[2] = (__bf16)acc[i][j][2];
                t4[3] = (__bf16)acc[i][j][3];
                *(bf16x4_t*)(cout + ((size_t)b * DD + col) * NN + nn2) = t4;
            }
        }
}

extern "C" void kernel_launch(void* const* d_in, const int* in_sizes, int n_in,
                              void* d_out, int out_size, void* d_ws, size_t ws_size,
                              hipStream_t stream) {
    const float* h   = (const float*)d_in[0];
    const float* adj = (const float*)d_in[1];
    const float* W   = (const float*)d_in[2];
    const float* cw  = (const float*)d_in[3];
    const float* cb  = (const float*)d_in[4];
    float* out = (float*)d_out;

    char* ws = (char*)d_ws;
    __bf16* adjn = (__bf16*)ws;                                   // 64 MB
    __bf16* c0   = (__bf16*)(ws + 67108864);                      // 8 MB
    __bf16* c1   = (__bf16*)(ws + 67108864 + 8388608);            // 8 MB
    __bf16* c2   = (__bf16*)(ws + 67108864 + 16777216);           // 8 MB (~88 MB total)

    k_pre<<<512 + BATCH * NN, 256, 0, stream>>>(h, W, adj, cw, out, c0, adjn);
    k_diffuse<false><<<dim3(NN / 64, DD / 128, BATCH), 256, 0, stream>>>(adjn, c0, c1, nullptr, nullptr, out, cw, cb);
    k_diffuse<false><<<dim3(NN / 64, DD / 128, BATCH), 256, 0, stream>>>(adjn, c1, c2, nullptr, nullptr, out, cw, cb);
    k_diffuse<true ><<<dim3(NN / 64, DD / 128, BATCH), 256, 0, stream>>>(adjn, c2, nullptr, c1, c2, out, cw, cb);
}

// Round 5
// 118.230 us; speedup vs baseline: 1.5959x; 1.1075x over previous
//
#include <hip/hip_runtime.h>
#include <hip/hip_bf16.h>
#include <cstdint>

// MultiRelationalGraphDiffusion: out = LeakyReLU( sum_k conv_w[k] * (adj_norm^k @ (h@W^T)) + conv_b )
// B=8, N=2048, D=256, K=4.
//
// Round-5 = Round-4 with compile fix: __builtin_amdgcn_cvt_f32_fp8 needs a LITERAL
// byte index -> unpack via helper with constant 0..3.
//
// Structure (lesson R3: never fuse big-LDS kernel with BW-bound grid):
//  - k_normadj: wave-per-row, zero LDS, fp8 e4m3 x256 output, pre-swizzled 8B chunks.
//  - k_htrans:  h@W^T via bf16x3 MFMA (fp32-grade). out = cw0*t; c0 = fp8(16*t).
//  - k_diffuse: fp8 MFMA 16x16x32_fp8_fp8, 64x128 tile, BK=64, double-buffered
//               stage-ahead-1 global_load_lds(16) — fp8 halves the byte-bound streams.
// Scales: adjS = 256*adj_norm, cS = 16*c -> acc = 4096*(adj@c); next cS = acc/256;
//         final tap = acc/4096; c1/c2 decode = u/16.

#define BATCH 8
#define NN    2048
#define DD    256
#define REPS  1e-9f
#define SLOPE 0.2f

typedef __bf16 bf16x8_t __attribute__((ext_vector_type(8)));
typedef __bf16 bf16x4_t __attribute__((ext_vector_type(4)));
typedef float  f32x4_t  __attribute__((ext_vector_type(4)));

__device__ __forceinline__ void gl2lds16(const void* g, void* l) {
    __builtin_amdgcn_global_load_lds(
        (const __attribute__((address_space(1))) unsigned int*)(uintptr_t)g,
        (__attribute__((address_space(3))) unsigned int*)(unsigned int)(uintptr_t)l,
        16, 0, 0);
}

// pack 4 f32 -> 4 fp8 e4m3 bytes (little-endian k-order)
__device__ __forceinline__ unsigned int pk_fp8x4(float a, float b, float c, float d) {
    int lo = __builtin_amdgcn_cvt_pk_fp8_f32(a, b, 0, false);
    return (unsigned int)__builtin_amdgcn_cvt_pk_fp8_f32(c, d, lo, true);
}

// unpack 4 fp8 e4m3 bytes -> f32x4 (literal byte-select indices required)
__device__ __forceinline__ f32x4_t cvt_f32_fp8x4(unsigned int u) {
    f32x4_t r;
    r[0] = __builtin_amdgcn_cvt_f32_fp8(u, 0);
    r[1] = __builtin_amdgcn_cvt_f32_fp8(u, 1);
    r[2] = __builtin_amdgcn_cvt_f32_fp8(u, 2);
    r[3] = __builtin_amdgcn_cvt_f32_fp8(u, 3);
    return r;
}

// swizzled byte position of logical byte n within a row keyed by `key`:
// 8B chunk within each 64B segment XORed by key.
__device__ __forceinline__ int swz(int n, int key) {
    return (n & ~63) | ((((n >> 3) & 7) ^ key) << 3) | (n & 7);
}

// ================= normadj: wave-per-row, no LDS, fp8 x256 output =================
__global__ __launch_bounds__(256) void k_normadj(const float* __restrict__ adj,
                                                 unsigned char* __restrict__ adjq) {
    const int l = threadIdx.x & 63;
    const int row = blockIdx.x * 4 + (threadIdx.x >> 6);   // b*NN + n
    const float* src = adj + (size_t)row * NN;
    f32x4_t v[8];
#pragma unroll
    for (int j = 0; j < 8; ++j) v[j] = *(const f32x4_t*)(src + (j * 64 + l) * 4);
    float s = 0.f;
#pragma unroll
    for (int j = 0; j < 8; ++j) s += v[j][0] + v[j][1] + v[j][2] + v[j][3];
#pragma unroll
    for (int m = 1; m < 64; m <<= 1) s += __shfl_xor(s, m, 64);
    const float sc = 256.0f / (s + REPS);
    const int key = row & 7;
    unsigned char* drow = adjq + (size_t)row * NN;
#pragma unroll
    for (int j = 0; j < 8; ++j) {
        const int n = (j * 64 + l) * 4;
        *(unsigned int*)(drow + swz(n, key)) =
            pk_fp8x4(v[j][0] * sc, v[j][1] * sc, v[j][2] * sc, v[j][3] * sc);
    }
}

// ================= htrans: bf16x3 MFMA; out = cw0*t, c0q = fp8(16t) =================
// tile 64(n) x 128(o), BK=64, 4 waves each 32x64 (2x4 frags of 16x16x32 bf16)
__global__ __launch_bounds__(256) void k_htrans(const float* __restrict__ h,
                                                const float* __restrict__ W,
                                                const float* __restrict__ convw,
                                                float* __restrict__ out,
                                                unsigned char* __restrict__ c0q) {
    __shared__ __align__(16) __bf16 Ah[64 * 64], Al[64 * 64];
    __shared__ __align__(16) __bf16 Bh[128 * 64], Bl[128 * 64];

    const int tid = threadIdx.x;
    const int n0 = blockIdx.x * 64, o0 = blockIdx.y * 128, b = blockIdx.z;
    const int lane = tid & 63, wv = tid >> 6;
    const int wr = wv >> 1, wc = wv & 1;
    const int rl = lane & 15, kq = lane >> 4;
    const int ar = tid >> 4, ac = (tid & 15) * 4;

    f32x4_t acc[2][4];
#pragma unroll
    for (int i = 0; i < 2; ++i)
#pragma unroll
        for (int j = 0; j < 4; ++j) acc[i][j] = (f32x4_t){0.f, 0.f, 0.f, 0.f};

    for (int kt = 0; kt < 4; ++kt) {
        const int k0 = kt * 64;
#pragma unroll
        for (int q = 0; q < 4; ++q) {
            const int r = q * 16 + ar;
            f32x4_t v = *(const f32x4_t*)(h + ((size_t)b * NN + n0 + r) * DD + k0 + ac);
            bf16x4_t hi4, lo4;
#pragma unroll
            for (int e = 0; e < 4; ++e) {
                float x = v[e];
                __bf16 hh = (__bf16)x;
                hi4[e] = hh;
                lo4[e] = (__bf16)(x - (float)hh);
            }
            const int off = r * 128 + (((ac >> 3) ^ (r & 7)) << 4) + (ac & 7) * 2;
            *(bf16x4_t*)((char*)Ah + off) = hi4;
            *(bf16x4_t*)((char*)Al + off) = lo4;
        }
#pragma unroll
        for (int q = 0; q < 8; ++q) {
            const int r = q * 16 + ar;
            f32x4_t v = *(const f32x4_t*)(W + (size_t)(o0 + r) * DD + k0 + ac);
            bf16x4_t hi4, lo4;
#pragma unroll
            for (int e = 0; e < 4; ++e) {
                float x = v[e];
                __bf16 hh = (__bf16)x;
                hi4[e] = hh;
                lo4[e] = (__bf16)(x - (float)hh);
            }
            const int off = r * 128 + (((ac >> 3) ^ (r & 7)) << 4) + (ac & 7) * 2;
            *(bf16x4_t*)((char*)Bh + off) = hi4;
            *(bf16x4_t*)((char*)Bl + off) = lo4;
        }
        __syncthreads();
#pragma unroll
        for (int s = 0; s < 2; ++s) {
            bf16x8_t ah[2], al[2], bh[4], bl[4];
#pragma unroll
            for (int i = 0; i < 2; ++i) {
                const int row = wr * 32 + i * 16 + rl;
                const int byo = row * 128 + (((s * 4 + kq) ^ (row & 7)) << 4);
                ah[i] = *(const bf16x8_t*)((const char*)Ah + byo);
                al[i] = *(const bf16x8_t*)((const char*)Al + byo);
            }
#pragma unroll
            for (int j = 0; j < 4; ++j) {
                const int o = wc * 64 + j * 16 + rl;
                const int byo = o * 128 + (((s * 4 + kq) ^ (o & 7)) << 4);
                bh[j] = *(const bf16x8_t*)((const char*)Bh + byo);
                bl[j] = *(const bf16x8_t*)((const char*)Bl + byo);
            }
#pragma unroll
            for (int i = 0; i < 2; ++i)
#pragma unroll
                for (int j = 0; j < 4; ++j) {
                    acc[i][j] = __builtin_amdgcn_mfma_f32_16x16x32_bf16(ah[i], bh[j], acc[i][j], 0, 0, 0);
                    acc[i][j] = __builtin_amdgcn_mfma_f32_16x16x32_bf16(al[i], bh[j], acc[i][j], 0, 0, 0);
                    acc[i][j] = __builtin_amdgcn_mfma_f32_16x16x32_bf16(ah[i], bl[j], acc[i][j], 0, 0, 0);
                }
        }
        __syncthreads();
    }

    const float cw0 = convw[0];
#pragma unroll
    for (int i = 0; i < 2; ++i)
#pragma unroll
        for (int j = 0; j < 4; ++j) {
            const int row0 = n0 + wr * 32 + i * 16 + kq * 4;
            const int col  = o0 + wc * 64 + j * 16 + rl;
            float* op = out + ((size_t)b * NN + row0) * DD + col;
#pragma unroll
            for (int r2 = 0; r2 < 4; ++r2) op[r2 * DD] = cw0 * acc[i][j][r2];
            // c0 = fp8(16 * t), transposed [b][o][n], pre-swizzled keyed by o&7
            *(unsigned int*)(c0q + ((size_t)b * DD + col) * NN + swz(row0, col & 7)) =
                pk_fp8x4(16.f * acc[i][j][0], 16.f * acc[i][j][1],
                         16.f * acc[i][j][2], 16.f * acc[i][j][3]);
        }
}

// ================= diffusion step (fp8, double-buffered, stage-ahead-1) =================
__device__ __forceinline__ void stage_tile_q(const unsigned char* __restrict__ aRow,
                                             const unsigned char* __restrict__ cRow,
                                             unsigned char* As, unsigned char* Bs,
                                             int wv, int sr, int sb, int k0) {
    gl2lds16(aRow + (size_t)(wv * 16 + sr) * NN + k0 + sb, As + wv * 1024);
#pragma unroll
    for (int q = 0; q < 2; ++q)
        gl2lds16(cRow + (size_t)((wv * 2 + q) * 16 + sr) * NN + k0 + sb,
                 Bs + (wv * 2 + q) * 1024);
}

template <bool LAST>
__global__ __launch_bounds__(256) void k_diffuse(const unsigned char* __restrict__ adjq,
                                                 const unsigned char* __restrict__ cinq,
                                                 unsigned char* __restrict__ coutq,
                                                 const unsigned char* __restrict__ c1q,
                                                 const unsigned char* __restrict__ c2q,
                                                 float* __restrict__ out,
                                                 const float* __restrict__ convw,
                                                 const float* __restrict__ convb) {
    __shared__ __align__(16) unsigned char As[2][64 * 64];    // 2 x 4 KB
    __shared__ __align__(16) unsigned char Bs[2][128 * 64];   // 2 x 8 KB

    const int tid = threadIdx.x;
    const int n0 = blockIdx.x * 64, o0 = blockIdx.y * 128, b = blockIdx.z;
    const int lane = tid & 63, wv = tid >> 6;
    const int wr = wv >> 1, wc = wv & 1;
    const int rl = lane & 15, kq = lane >> 4;
    const int sr = lane >> 2, sb = (lane & 3) * 16;   // staging: row-in-chunk, 16B slot

    const unsigned char* aRow = adjq + (size_t)b * NN * NN + (size_t)n0 * NN;
    const unsigned char* cRow = cinq + (size_t)b * DD * NN + (size_t)o0 * NN;

    f32x4_t acc[2][4];
#pragma unroll
    for (int i = 0; i < 2; ++i)
#pragma unroll
        for (int j = 0; j < 4; ++j) acc[i][j] = (f32x4_t){0.f, 0.f, 0.f, 0.f};

    stage_tile_q(aRow, cRow, As[0], Bs[0], wv, sr, sb, 0);
    __syncthreads();

#pragma unroll 2
    for (int t = 0; t < NN / 64; ++t) {
        const int pb = t & 1;
        if (t < NN / 64 - 1)
            stage_tile_q(aRow, cRow, As[pb ^ 1], Bs[pb ^ 1], wv, sr, sb, (t + 1) * 64);
        const unsigned char* Ac = As[pb];
        const unsigned char* Bc = Bs[pb];
#pragma unroll
        for (int s = 0; s < 2; ++s) {
            long a[2], bb[4];
#pragma unroll
            for (int i = 0; i < 2; ++i) {
                const int row = wr * 32 + i * 16 + rl;
                a[i] = *(const long*)(Ac + row * 64 + (((s * 4 + kq) ^ (row & 7)) << 3));
            }
#pragma unroll
            for (int j = 0; j < 4; ++j) {
                const int o = wc * 64 + j * 16 + rl;
                bb[j] = *(const long*)(Bc + o * 64 + (((s * 4 + kq) ^ (o & 7)) << 3));
            }
#pragma unroll
            for (int i = 0; i < 2; ++i)
#pragma unroll
                for (int j = 0; j < 4; ++j)
                    acc[i][j] = __builtin_amdgcn_mfma_f32_16x16x32_fp8_fp8(a[i], bb[j], acc[i][j], 0, 0, 0);
        }
        __syncthreads();   // drains vmcnt (stage-ahead) + lgkm; protects buffer reuse
    }

    // ---- epilogue: D frag col=lane&15, row=(lane>>4)*4+reg (dtype-independent) ----
#pragma unroll
    for (int i = 0; i < 2; ++i)
#pragma unroll
        for (int j = 0; j < 4; ++j) {
            const int row0 = n0 + wr * 32 + i * 16 + kq * 4;
            const int col  = o0 + wc * 64 + j * 16 + rl;
            if (LAST) {
                const float cw1 = convw[1], cw2 = convw[2], cw3 = convw[3];
                const float cb  = convb[0];
                const float ru = 1.0f / 16.0f, rf = 1.0f / 4096.0f;
                float* op = out + ((size_t)b * NN + row0) * DD + col;
                const int sa = swz(row0, col & 7);
                f32x4_t u1 = cvt_f32_fp8x4(*(const unsigned int*)(c1q + ((size_t)b * DD + col) * NN + sa));
                f32x4_t u2 = cvt_f32_fp8x4(*(const unsigned int*)(c2q + ((size_t)b * DD + col) * NN + sa));
#pragma unroll
                for (int r2 = 0; r2 < 4; ++r2) {
                    float v = op[r2 * DD] + cw1 * ru * u1[r2] + cw2 * ru * u2[r2]
                            + cw3 * rf * acc[i][j][r2] + cb;
                    op[r2 * DD] = v >= 0.0f ? v : SLOPE * v;
                }
            } else {
                const float rs = 1.0f / 256.0f;   // acc -> 16*c_next
                *(unsigned int*)(coutq + ((size_t)b * DD + col) * NN + swz(row0, col & 7)) =
                    pk_fp8x4(rs * acc[i][j][0], rs * acc[i][j][1],
                             rs * acc[i][j][2], rs * acc[i][j][3]);
            }
        }
}

extern "C" void kernel_launch(void* const* d_in, const int* in_sizes, int n_in,
                              void* d_out, int out_size, void* d_ws, size_t ws_size,
                              hipStream_t stream) {
    const float* h   = (const float*)d_in[0];
    const float* adj = (const float*)d_in[1];
    const float* W   = (const float*)d_in[2];
    const float* cw  = (const float*)d_in[3];
    const float* cb  = (const float*)d_in[4];
    float* out = (float*)d_out;

    char* ws = (char*)d_ws;
    unsigned char* adjq = (unsigned char*)ws;                         // 32 MB
    unsigned char* c0q  = (unsigned char*)(ws + 33554432);            // 4 MB
    unsigned char* c1q  = (unsigned char*)(ws + 33554432 + 4194304);  // 4 MB
    unsigned char* c2q  = (unsigned char*)(ws + 33554432 + 8388608);  // 4 MB (~44 MB)

    k_normadj<<<BATCH * NN / 4, 256, 0, stream>>>(adj, adjq);
    k_htrans<<<dim3(NN / 64, DD / 128, BATCH), 256, 0, stream>>>(h, W, cw, out, c0q);
    k_diffuse<false><<<dim3(NN / 64, DD / 128, BATCH), 256, 0, stream>>>(adjq, c0q, c1q, nullptr, nullptr, out, cw, cb);
    k_diffuse<false><<<dim3(NN / 64, DD / 128, BATCH), 256, 0, stream>>>(adjq, c1q, c2q, nullptr, nullptr, out, cw, cb);
    k_diffuse<true ><<<dim3(NN / 64, DD / 128, BATCH), 256, 0, stream>>>(adjq, c2q, nullptr, c1q, c2q, out, cw, cb);
}